// Round 2
// baseline (1101.004 us; speedup 1.0000x reference)
//
#include <hip/hip_runtime.h>
#include <hip/hip_bf16.h>

#define N_NODES 100000
#define N_EDGES 600000
#define HD 128
#define NBC 384
#define LST 136  // LDS row stride (bf16 elems): 128 + 8 pad (272B) kills power-of-2 bank conflicts

typedef __attribute__((ext_vector_type(8))) short s8v;
typedef __attribute__((ext_vector_type(4))) float f4v;
typedef __hip_bfloat16 bf16;

static __device__ __forceinline__ float bf2f(bf16 v) { return __bfloat162float(v); }
static __device__ __forceinline__ bf16 f2bf(float v) { return __float2bfloat16(v); }

// ================= dtype detection =================
// flags[0]: 1 if float inputs are fp32, 0 if bf16.  flags[1]: 1 if ints are int64.
// W_enc ~ N(0, 0.05^2): real bf16 elements are tiny; fp32-read-as-bf16 yields random
// exponents (44% of garbage words exceed 1e4, ~1% are NaN encodings).
__global__ void k_detect(const unsigned short* __restrict__ wraw,
                         const int* __restrict__ eraw, int* __restrict__ flags) {
    if (threadIdx.x == 0 && blockIdx.x == 0) {
        int fp32 = 0;
        for (int i = 0; i < 1024; i++) {
            unsigned int u = ((unsigned int)wraw[i]) << 16;
            float f = fabsf(__uint_as_float(u));
            if (!(f <= 1e4f)) fp32 = 1;  // catches huge AND NaN
        }
        int i64 = (eraw[1] == 0 && eraw[3] == 0 && eraw[5] == 0 && eraw[7] == 0) ? 1 : 0;
        flags[0] = fp32;
        flags[1] = i64;
    }
}

// ================= canonical conversion (all float inputs -> bf16) =================
// block ranges per tensor (compile-time): cf 1.5M, slf 100K, z 3.2M, tr 384,
// Wenc 6144, benc 128, Wm 32768, bm 128, Wu 49152, bu 128
#define B_CF 5860
#define C1 (B_CF)            // 5860
#define C2 (C1 + 391)        // slf
#define C3 (C2 + 12500)      // z
#define C4 (C3 + 2)          // tr
#define C5 (C4 + 24)         // Wenc
#define C6 (C5 + 1)          // benc
#define C7 (C6 + 128)        // Wm
#define C8 (C7 + 1)          // bm
#define C9 (C8 + 192)        // Wu
#define C10 (C9 + 1)         // bu
__global__ void k_cvt_all(const int* __restrict__ flags,
                          const void* s0, const void* s1, const void* s2, const void* s3,
                          const void* s4, const void* s5, const void* s6, const void* s7,
                          const void* s8, const void* s9,
                          bf16* d0, bf16* d1, bf16* d2, bf16* d3, bf16* d4,
                          bf16* d5, bf16* d6, bf16* d7, bf16* d8, bf16* d9) {
    int b = blockIdx.x;
    const void* src; bf16* dst; int n, lb;
    if (b < C1)       { src = s0; dst = d0; n = 1500000; lb = b; }
    else if (b < C2)  { src = s1; dst = d1; n = 100000;  lb = b - C1; }
    else if (b < C3)  { src = s2; dst = d2; n = 3200000; lb = b - C2; }
    else if (b < C4)  { src = s3; dst = d3; n = 384;     lb = b - C3; }
    else if (b < C5)  { src = s4; dst = d4; n = 6144;    lb = b - C4; }
    else if (b < C6)  { src = s5; dst = d5; n = 128;     lb = b - C5; }
    else if (b < C7)  { src = s6; dst = d6; n = 32768;   lb = b - C6; }
    else if (b < C8)  { src = s7; dst = d7; n = 128;     lb = b - C7; }
    else if (b < C9)  { src = s8; dst = d8; n = 49152;   lb = b - C8; }
    else              { src = s9; dst = d9; n = 128;     lb = b - C9; }
    int i = lb * 256 + threadIdx.x;
    if (i < n) {
        if (flags[0]) dst[i] = f2bf(((const float*)src)[i]);
        else          dst[i] = ((const bf16*)src)[i];
    }
}

#define B_E 4688
__global__ void k_cvt_ints(const int* __restrict__ flags, const int* __restrict__ e,
                           const int* __restrict__ cc, int* __restrict__ ec,
                           int* __restrict__ ccc) {
    int i64 = flags[1];
    int b = blockIdx.x;
    if (b < B_E) {
        int i = b * 256 + threadIdx.x;
        if (i < 2 * N_EDGES) ec[i] = i64 ? e[2 * i] : e[i];
    } else {
        int i = (b - B_E) * 256 + threadIdx.x;
        if (i < N_NODES) ccc[i] = i64 ? cc[2 * i] : cc[i];
    }
}

// ================= weight transpose: W[k][n] -> Wt[n][k] =================
__global__ void k_prep_w(const bf16* __restrict__ Wm, const bf16* __restrict__ Wu,
                         bf16* __restrict__ Wmt, bf16* __restrict__ Wut) {
    int i = blockIdx.x * 256 + threadIdx.x;
    if (i < 128 * 256) {
        int n = i >> 8, k = i & 255;
        Wmt[i] = Wm[k * 128 + n];
    } else {
        int j = i - 128 * 256;
        if (j < 128 * 384) {
            int n = j / 384, k = j - n * 384;
            Wut[j] = Wu[k * 128 + n];
        }
    }
}

// ================= encoder: x = concat(cf, slf, z) @ W_enc + b_enc =================
__global__ void k_encoder(const bf16* __restrict__ cf, const bf16* __restrict__ slf,
                          const bf16* __restrict__ z, const bf16* __restrict__ W,
                          const bf16* __restrict__ b, float* __restrict__ x,
                          bf16* __restrict__ xb) {
    __shared__ float in[2][48];
    int half = threadIdx.x >> 7, t = threadIdx.x & 127;
    int node = blockIdx.x * 2 + half;
    if (t < 48) {
        float v;
        if (t < 15) v = bf2f(cf[node * 15 + t]);
        else if (t == 15) v = bf2f(slf[node]);
        else v = bf2f(z[node * 32 + (t - 16)]);
        in[half][t] = v;
    }
    __syncthreads();
    float acc = bf2f(b[t]);
#pragma unroll 8
    for (int k = 0; k < 48; k++) acc += in[half][k] * bf2f(W[k * 128 + t]);
    size_t idx = (size_t)node * HD + t;
    x[idx] = acc;
    xb[idx] = f2bf(acc);
}

// ================= CSR build =================
__global__ void k_count_edges(const int* __restrict__ e, int* __restrict__ deg) {
    int i = blockIdx.x * 256 + threadIdx.x;
    if (i < N_EDGES) atomicAdd(&deg[e[N_EDGES + i]], 1);
}
__global__ void k_count_nodes(const int* __restrict__ cc, int* __restrict__ ccount) {
    int i = blockIdx.x * 256 + threadIdx.x;
    if (i < N_NODES) atomicAdd(&ccount[cc[i]], 1);
}

__global__ void k_scan_nodes(const int* __restrict__ deg, int* __restrict__ rowptr,
                             int* __restrict__ cursor) {
    __shared__ int sd[1024];
    int t = threadIdx.x;
    const int T = 1024;
    const int chunk = (N_NODES + T - 1) / T;  // 98
    int lo = t * chunk, hi = min(lo + chunk, N_NODES);
    int p = 0;
    for (int i = lo; i < hi; i++) p += deg[i];
    sd[t] = p;
    __syncthreads();
    for (int off = 1; off < T; off <<= 1) {
        int v = (t >= off) ? sd[t - off] : 0;
        __syncthreads();
        sd[t] += v;
        __syncthreads();
    }
    int run = (t == 0) ? 0 : sd[t - 1];
    for (int i = lo; i < hi; i++) {
        rowptr[i] = run;
        cursor[i] = run;
        run += deg[i];
    }
    if (hi == N_NODES && lo < N_NODES) rowptr[N_NODES] = run;
}

__global__ void k_scan_clusters(const int* __restrict__ ccount, int* __restrict__ coff,
                                int* __restrict__ ccur) {
    __shared__ int sd[512];
    int t = threadIdx.x;
    sd[t] = (t < NBC) ? ccount[t] : 0;
    __syncthreads();
    for (int off = 1; off < 512; off <<= 1) {
        int v = (t >= off) ? sd[t - off] : 0;
        __syncthreads();
        sd[t] += v;
        __syncthreads();
    }
    if (t < NBC) {
        int ex = (t == 0) ? 0 : sd[t - 1];
        coff[t] = ex;
        ccur[t] = ex;
        if (t == NBC - 1) coff[NBC] = sd[t];
    }
}

__global__ void k_fill_edges(const int* __restrict__ e, int* __restrict__ cursor,
                             int* __restrict__ colx) {
    int i = blockIdx.x * 256 + threadIdx.x;
    if (i < N_EDGES) {
        int d = e[N_EDGES + i];
        int p = atomicAdd(&cursor[d], 1);
        colx[p] = e[i];
    }
}
__global__ void k_fill_nodes(const int* __restrict__ cc, int* __restrict__ ccur,
                             int* __restrict__ cnodes) {
    int i = blockIdx.x * 256 + threadIdx.x;
    if (i < N_NODES) {
        int p = atomicAdd(&ccur[cc[i]], 1);
        cnodes[p] = i;
    }
}

// ================= per-layer: mean of x[src] over incoming edges =================
__global__ void k_aggregate(const bf16* __restrict__ xb, const int* __restrict__ rowptr,
                            const int* __restrict__ colx, bf16* __restrict__ mb) {
    int wave = threadIdx.x >> 6, lane = threadIdx.x & 63;
    int node = blockIdx.x * 4 + wave;
    if (node >= N_NODES) return;
    int lo = rowptr[node], hi = rowptr[node + 1];
    float a0 = 0.f, a1 = 0.f;
    int j = lo;
    int nx = (j < hi) ? colx[j] : 0;
    while (j < hi) {
        int s = nx;
        j++;
        if (j < hi) nx = colx[j];  // prefetch next index to overlap with gather
        __hip_bfloat162 v = *((const __hip_bfloat162*)(xb + (size_t)s * HD) + lane);
        a0 += bf2f(v.x);
        a1 += bf2f(v.y);
    }
    int d = hi - lo;
    float inv = 1.0f / (float)(d > 1 ? d : 1);
    __hip_bfloat162 o;
    o.x = f2bf(a0 * inv);
    o.y = f2bf(a1 * inv);
    *((__hip_bfloat162*)(mb + (size_t)node * HD) + lane) = o;
}

// ================= per-layer: cluster pooling =================
__global__ void k_pool_partial(const float* __restrict__ x, const int* __restrict__ coff,
                               const int* __restrict__ cnodes, float* __restrict__ pf) {
    int cl = blockIdx.x >> 2, seg = blockIdx.x & 3;
    int lo = coff[cl], hi = coff[cl + 1];
    int cnt = hi - lo;
    int per = (cnt + 3) >> 2;
    int s0 = lo + seg * per;
    int s1 = min(s0 + per, hi);
    int col = threadIdx.x & 127, half = threadIdx.x >> 7;
    float a = 0.f;
    for (int i = s0 + half; i < s1; i += 2) a += x[(size_t)cnodes[i] * HD + col];
    __shared__ float red[256];
    red[threadIdx.x] = a;
    __syncthreads();
    if (half == 0) {
        float s = red[col] + red[col + 128];
        atomicAdd(&pf[cl * HD + col], s);
    }
}
__global__ void k_pool_final(const float* __restrict__ pf, const int* __restrict__ ccount,
                             const bf16* __restrict__ tr, bf16* __restrict__ pooled) {
    int i = blockIdx.x * 256 + threadIdx.x;  // 384*128
    int cl = i >> 7;
    int c = ccount[cl];
    float v = pf[i] / (float)(c > 1 ? c : 1) * bf2f(tr[cl]);
    pooled[i] = f2bf(v);
}

// ================= per-layer fused update (two chained MFMA GEMMs + residual) ========
// aggr = mask(deg>0) * ([x | m] @ Wm + bm)         (K=256)
// upd  = leaky([x | aggr | pooled[cc]] @ Wu + bu)  (K=384)
// x   += upd  (fp32 master + bf16 shadow)
// NOTE: xb and xbo alias (same buffer) -> NO __restrict__ on either.
__global__ __launch_bounds__(256) void k_update(
    const bf16* xb, const bf16* __restrict__ mb, const bf16* __restrict__ pooled,
    const bf16* __restrict__ Wmt, const bf16* __restrict__ Wut,
    const bf16* __restrict__ bm, const bf16* __restrict__ bu,
    const int* __restrict__ cc, const int* __restrict__ deg,
    float* __restrict__ x, bf16* xbo) {
    __shared__ __align__(16) short As[64 * LST];
    __shared__ __align__(16) short Ms[64 * LST];
    __shared__ __align__(16) short Gs[64 * LST];
    int tid = threadIdx.x;
    int r0 = blockIdx.x * 64;

    // stage x,m tiles (16B chunks)
    for (int i = tid; i < 1024; i += 256) {
        int row = i >> 4, ch = i & 15;
        int gr = r0 + row;
        s8v vx = {0, 0, 0, 0, 0, 0, 0, 0};
        s8v vm = {0, 0, 0, 0, 0, 0, 0, 0};
        if (gr < N_NODES) {
            vx = *(const s8v*)((const short*)xb + (size_t)gr * HD + ch * 8);
            vm = *(const s8v*)((const short*)mb + (size_t)gr * HD + ch * 8);
        }
        *(s8v*)(As + row * LST + ch * 8) = vx;
        *(s8v*)(Ms + row * LST + ch * 8) = vm;
    }
    __syncthreads();

    int wave = tid >> 6, lane = tid & 63, quad = lane >> 4, nidx = lane & 15;
    int colbase = wave * 32;  // each wave owns 32 output cols -> 4x B-frag reuse
    f4v acc[4][2];
#pragma unroll
    for (int rt = 0; rt < 4; rt++)
#pragma unroll
        for (int ct = 0; ct < 2; ct++) acc[rt][ct] = (f4v){0.f, 0.f, 0.f, 0.f};

    // phase 1: [x | m] @ Wm
#pragma unroll
    for (int s = 0; s < 8; s++) {
        int k0 = s * 32;
        const short* Ab = (s < 4) ? As : Ms;
        int kk = (s < 4) ? k0 : (k0 - 128);
        s8v afr[4];
#pragma unroll
        for (int rt = 0; rt < 4; rt++)
            afr[rt] = *(const s8v*)(Ab + (rt * 16 + nidx) * LST + kk + quad * 8);
#pragma unroll
        for (int ct = 0; ct < 2; ct++) {
            s8v bfr = *(const s8v*)((const short*)Wmt + (colbase + ct * 16 + nidx) * 256 + k0 + quad * 8);
#pragma unroll
            for (int rt = 0; rt < 4; rt++)
                acc[rt][ct] = __builtin_amdgcn_mfma_f32_16x16x32_bf16(afr[rt], bfr, acc[rt][ct], 0, 0, 0);
        }
    }
    // epilogue 1 -> Gs (bf16, A-layout for phase 2)
#pragma unroll
    for (int ct = 0; ct < 2; ct++) {
        int col = colbase + ct * 16 + nidx;
        float bmv = bf2f(bm[col]);
#pragma unroll
        for (int rt = 0; rt < 4; rt++) {
#pragma unroll
            for (int r = 0; r < 4; r++) {
                int lrow = rt * 16 + quad * 4 + r;
                int gr = r0 + lrow;
                int d = (gr < N_NODES) ? deg[gr] : 0;
                float v = (d > 0) ? (acc[rt][ct][r] + bmv) : 0.f;
                bf16 h = f2bf(v);
                Gs[lrow * LST + col] = *(short*)&h;
            }
        }
    }
    __syncthreads();

    // phase 2: [x | aggr | pooled[cc]] @ Wu
    int cci[4];
#pragma unroll
    for (int rt = 0; rt < 4; rt++) {
        int gr = r0 + rt * 16 + nidx;
        cci[rt] = (gr < N_NODES) ? cc[gr] : 0;
    }
#pragma unroll
    for (int rt = 0; rt < 4; rt++)
#pragma unroll
        for (int ct = 0; ct < 2; ct++) acc[rt][ct] = (f4v){0.f, 0.f, 0.f, 0.f};
#pragma unroll
    for (int s = 0; s < 12; s++) {
        int k0 = s * 32;
        s8v afr[4];
        if (s < 8) {
            const short* Ab = (s < 4) ? As : Gs;
            int kk = (s < 4) ? k0 : (k0 - 128);
#pragma unroll
            for (int rt = 0; rt < 4; rt++)
                afr[rt] = *(const s8v*)(Ab + (rt * 16 + nidx) * LST + kk + quad * 8);
        } else {
            int kk = k0 - 256;
#pragma unroll
            for (int rt = 0; rt < 4; rt++)
                afr[rt] = *(const s8v*)((const short*)pooled + (size_t)cci[rt] * HD + kk + quad * 8);
        }
#pragma unroll
        for (int ct = 0; ct < 2; ct++) {
            s8v bfr = *(const s8v*)((const short*)Wut + (colbase + ct * 16 + nidx) * 384 + k0 + quad * 8);
#pragma unroll
            for (int rt = 0; rt < 4; rt++)
                acc[rt][ct] = __builtin_amdgcn_mfma_f32_16x16x32_bf16(afr[rt], bfr, acc[rt][ct], 0, 0, 0);
        }
    }
    // epilogue 2: bias, leaky-relu, residual
#pragma unroll
    for (int ct = 0; ct < 2; ct++) {
        int col = colbase + ct * 16 + nidx;
        float buv = bf2f(bu[col]);
#pragma unroll
        for (int rt = 0; rt < 4; rt++) {
#pragma unroll
            for (int r = 0; r < 4; r++) {
                int lrow = rt * 16 + quad * 4 + r;
                int gr = r0 + lrow;
                if (gr < N_NODES) {
                    float v = acc[rt][ct][r] + buv;
                    v = (v > 0.f) ? v : 0.01f * v;
                    size_t idx = (size_t)gr * HD + col;
                    float nv = x[idx] + v;
                    x[idx] = nv;
                    xbo[idx] = f2bf(nv);
                }
            }
        }
    }
}

// ================= output (dtype-branched) =================
__global__ void k_output(const int* __restrict__ flags, const float* __restrict__ x,
                         void* __restrict__ out) {
    int i = blockIdx.x * 256 + threadIdx.x;  // 50000 blocks * 256 = 12.8M exactly
    if (flags[0]) ((float*)out)[i] = x[i];
    else ((bf16*)out)[i] = f2bf(x[i]);
}

extern "C" void kernel_launch(void* const* d_in, const int* in_sizes, int n_in,
                              void* d_out, int out_size, void* d_ws, size_t ws_size,
                              hipStream_t stream) {
    const void* cf_r = d_in[0];
    const void* slf_r = d_in[1];
    const void* z_r = d_in[2];
    const void* tr_r = d_in[3];
    const void* Wenc_r = d_in[4];
    const void* benc_r = d_in[5];
    const void* Wm_r = d_in[6];
    const void* bm_r = d_in[7];
    const void* Wu_r = d_in[8];
    const void* bu_r = d_in[9];
    const int* e_r = (const int*)d_in[10];
    const int* cc_r = (const int*)d_in[11];
    // d_in[12] = cfb, unused by the reference

    char* w = (char*)d_ws;
    auto alloc = [&](size_t bytes) -> char* {
        char* p = w;
        w += (bytes + 63) & ~(size_t)63;
        return p;
    };
    float* x = (float*)alloc((size_t)N_NODES * HD * 4);
    bf16* xb = (bf16*)alloc((size_t)N_NODES * HD * 2);
    bf16* mb = (bf16*)alloc((size_t)N_NODES * HD * 2);
    bf16* Wmt = (bf16*)alloc(128 * 256 * 2);
    bf16* Wut = (bf16*)alloc(128 * 384 * 2);
    float* pooledf = (float*)alloc(NBC * HD * 4);
    bf16* pooled = (bf16*)alloc(NBC * HD * 2);
    int* deg = (int*)alloc(N_NODES * 4);
    int* rowptr = (int*)alloc((N_NODES + 1) * 4);
    int* cursor = (int*)alloc(N_NODES * 4);
    int* colx = (int*)alloc(N_EDGES * 4);
    int* ccount = (int*)alloc(NBC * 4);
    int* coff = (int*)alloc((NBC + 1) * 4);
    int* ccur = (int*)alloc(NBC * 4);
    int* cnodes = (int*)alloc(N_NODES * 4);
    int* flags = (int*)alloc(64);
    // canonical bf16 / int32 inputs
    bf16* cfc = (bf16*)alloc(1500000 * 2);
    bf16* slfc = (bf16*)alloc(100000 * 2);
    bf16* zc = (bf16*)alloc(3200000 * 2);
    bf16* trc = (bf16*)alloc(384 * 2);
    bf16* Wencc = (bf16*)alloc(6144 * 2);
    bf16* bencc = (bf16*)alloc(128 * 2);
    bf16* Wmc = (bf16*)alloc(32768 * 2);
    bf16* bmc = (bf16*)alloc(128 * 2);
    bf16* Wuc = (bf16*)alloc(49152 * 2);
    bf16* buc = (bf16*)alloc(128 * 2);
    int* ec = (int*)alloc(2 * N_EDGES * 4);
    int* ccc = (int*)alloc(N_NODES * 4);

    // dtype detection + canonical conversion
    k_detect<<<1, 64, 0, stream>>>((const unsigned short*)Wenc_r, e_r, flags);
    k_cvt_all<<<C10, 256, 0, stream>>>(flags, cf_r, slf_r, z_r, tr_r, Wenc_r, benc_r,
                                       Wm_r, bm_r, Wu_r, bu_r,
                                       cfc, slfc, zc, trc, Wencc, bencc, Wmc, bmc, Wuc, buc);
    k_cvt_ints<<<B_E + 391, 256, 0, stream>>>(flags, e_r, cc_r, ec, ccc);

    // weight prep + encoder
    k_prep_w<<<(128 * 256 + 128 * 384) / 256, 256, 0, stream>>>(Wmc, Wuc, Wmt, Wut);
    k_encoder<<<N_NODES / 2, 256, 0, stream>>>(cfc, slfc, zc, Wencc, bencc, x, xb);

    // CSR build (edges by dst, nodes by cluster)
    hipMemsetAsync(deg, 0, (size_t)N_NODES * 4, stream);
    hipMemsetAsync(ccount, 0, (size_t)NBC * 4, stream);
    k_count_edges<<<(N_EDGES + 255) / 256, 256, 0, stream>>>(ec, deg);
    k_count_nodes<<<(N_NODES + 255) / 256, 256, 0, stream>>>(ccc, ccount);
    k_scan_nodes<<<1, 1024, 0, stream>>>(deg, rowptr, cursor);
    k_scan_clusters<<<1, 512, 0, stream>>>(ccount, coff, ccur);
    k_fill_edges<<<(N_EDGES + 255) / 256, 256, 0, stream>>>(ec, cursor, colx);
    k_fill_nodes<<<(N_NODES + 255) / 256, 256, 0, stream>>>(ccc, ccur, cnodes);

    for (int layer = 0; layer < 3; layer++) {
        hipMemsetAsync(pooledf, 0, (size_t)NBC * HD * 4, stream);
        k_aggregate<<<N_NODES / 4, 256, 0, stream>>>(xb, rowptr, colx, mb);
        k_pool_partial<<<NBC * 4, 256, 0, stream>>>(x, coff, cnodes, pooledf);
        k_pool_final<<<NBC * HD / 256, 256, 0, stream>>>(pooledf, ccount, trc, pooled);
        k_update<<<(N_NODES + 63) / 64, 256, 0, stream>>>(xb, mb, pooled, Wmt, Wut,
                                                          bmc, buc, ccc, deg, x, xb);
    }

    k_output<<<(N_NODES * HD) / 256, 256, 0, stream>>>(flags, x, d_out);
}

// Round 3
// 884.719 us; speedup vs baseline: 1.2445x; 1.2445x over previous
//
#include <hip/hip_runtime.h>
#include <hip/hip_bf16.h>

#define N_NODES 100000
#define N_EDGES 600000
#define HD 128
#define NBC 384
#define LST 136  // LDS row stride (bf16 elems): 128 + 8 pad (272B) kills power-of-2 bank conflicts
#define SCAN_B 98  // ceil(N_NODES/1024)

typedef __attribute__((ext_vector_type(8))) short s8v;
typedef __attribute__((ext_vector_type(4))) float f4v;
typedef __hip_bfloat16 bf16;

static __device__ __forceinline__ float bf2f(bf16 v) { return __bfloat162float(v); }
static __device__ __forceinline__ bf16 f2bf(float v) { return __float2bfloat16(v); }

// ================= dtype detection =================
// flags[0]: 1 if float inputs are fp32, 0 if bf16.  flags[1]: 1 if ints are int64.
__global__ void k_detect(const unsigned short* __restrict__ wraw,
                         const int* __restrict__ eraw, int* __restrict__ flags) {
    if (threadIdx.x == 0 && blockIdx.x == 0) {
        int fp32 = 0;
        for (int i = 0; i < 1024; i++) {
            unsigned int u = ((unsigned int)wraw[i]) << 16;
            float f = fabsf(__uint_as_float(u));
            if (!(f <= 1e4f)) fp32 = 1;  // catches huge AND NaN
        }
        int i64 = (eraw[1] == 0 && eraw[3] == 0 && eraw[5] == 0 && eraw[7] == 0) ? 1 : 0;
        flags[0] = fp32;
        flags[1] = i64;
    }
}

// ================= canonical conversion (all float inputs -> bf16) =================
#define B_CF 5860
#define C1 (B_CF)
#define C2 (C1 + 391)
#define C3 (C2 + 12500)
#define C4 (C3 + 2)
#define C5 (C4 + 24)
#define C6 (C5 + 1)
#define C7 (C6 + 128)
#define C8 (C7 + 1)
#define C9 (C8 + 192)
#define C10 (C9 + 1)
__global__ void k_cvt_all(const int* __restrict__ flags,
                          const void* s0, const void* s1, const void* s2, const void* s3,
                          const void* s4, const void* s5, const void* s6, const void* s7,
                          const void* s8, const void* s9,
                          bf16* d0, bf16* d1, bf16* d2, bf16* d3, bf16* d4,
                          bf16* d5, bf16* d6, bf16* d7, bf16* d8, bf16* d9) {
    int b = blockIdx.x;
    const void* src; bf16* dst; int n, lb;
    if (b < C1)       { src = s0; dst = d0; n = 1500000; lb = b; }
    else if (b < C2)  { src = s1; dst = d1; n = 100000;  lb = b - C1; }
    else if (b < C3)  { src = s2; dst = d2; n = 3200000; lb = b - C2; }
    else if (b < C4)  { src = s3; dst = d3; n = 384;     lb = b - C3; }
    else if (b < C5)  { src = s4; dst = d4; n = 6144;    lb = b - C4; }
    else if (b < C6)  { src = s5; dst = d5; n = 128;     lb = b - C5; }
    else if (b < C7)  { src = s6; dst = d6; n = 32768;   lb = b - C6; }
    else if (b < C8)  { src = s7; dst = d7; n = 128;     lb = b - C7; }
    else if (b < C9)  { src = s8; dst = d8; n = 49152;   lb = b - C8; }
    else              { src = s9; dst = d9; n = 128;     lb = b - C9; }
    int i = lb * 256 + threadIdx.x;
    if (i < n) {
        if (flags[0]) dst[i] = f2bf(((const float*)src)[i]);
        else          dst[i] = ((const bf16*)src)[i];
    }
}

#define B_E 4688
__global__ void k_cvt_ints(const int* __restrict__ flags, const int* __restrict__ e,
                           const int* __restrict__ cc, int* __restrict__ ec,
                           int* __restrict__ ccc) {
    int i64 = flags[1];
    int b = blockIdx.x;
    if (b < B_E) {
        int i = b * 256 + threadIdx.x;
        if (i < 2 * N_EDGES) ec[i] = i64 ? e[2 * i] : e[i];
    } else {
        int i = (b - B_E) * 256 + threadIdx.x;
        if (i < N_NODES) ccc[i] = i64 ? cc[2 * i] : cc[i];
    }
}

// ================= weight transpose: W[k][n] -> Wt[n][k] =================
__global__ void k_prep_w(const bf16* __restrict__ Wm, const bf16* __restrict__ Wu,
                         bf16* __restrict__ Wmt, bf16* __restrict__ Wut) {
    int i = blockIdx.x * 256 + threadIdx.x;
    if (i < 128 * 256) {
        int n = i >> 8, k = i & 255;
        Wmt[i] = Wm[k * 128 + n];
    } else {
        int j = i - 128 * 256;
        if (j < 128 * 384) {
            int n = j / 384, k = j - n * 384;
            Wut[j] = Wu[k * 128 + n];
        }
    }
}

// ================= encoder =================
__global__ void k_encoder(const bf16* __restrict__ cf, const bf16* __restrict__ slf,
                          const bf16* __restrict__ z, const bf16* __restrict__ W,
                          const bf16* __restrict__ b, float* __restrict__ x,
                          bf16* __restrict__ xb) {
    __shared__ float in[2][48];
    int half = threadIdx.x >> 7, t = threadIdx.x & 127;
    int node = blockIdx.x * 2 + half;
    if (t < 48) {
        float v;
        if (t < 15) v = bf2f(cf[node * 15 + t]);
        else if (t == 15) v = bf2f(slf[node]);
        else v = bf2f(z[node * 32 + (t - 16)]);
        in[half][t] = v;
    }
    __syncthreads();
    float acc = bf2f(b[t]);
#pragma unroll 8
    for (int k = 0; k < 48; k++) acc += in[half][k] * bf2f(W[k * 128 + t]);
    size_t idx = (size_t)node * HD + t;
    x[idx] = acc;
    xb[idx] = f2bf(acc);
}

// ================= CSR build =================
__global__ void k_count_edges(const int* __restrict__ e, int* __restrict__ deg) {
    int i = blockIdx.x * 256 + threadIdx.x;
    if (i < N_EDGES) atomicAdd(&deg[e[N_EDGES + i]], 1);
}
__global__ void k_count_nodes(const int* __restrict__ cc, int* __restrict__ ccount) {
    int i = blockIdx.x * 256 + threadIdx.x;
    if (i < N_NODES) atomicAdd(&ccount[cc[i]], 1);
}

// ---- parallel 3-pass scan of deg -> rowptr/cursor (replaces 231us single-block scan) ----
__global__ void k_scan_a(const int* __restrict__ deg, int* __restrict__ rowptr,
                         int* __restrict__ bsum) {
    __shared__ int sd[1024];
    int t = threadIdx.x;
    int i = blockIdx.x * 1024 + t;
    int v = (i < N_NODES) ? deg[i] : 0;
    sd[t] = v;
    __syncthreads();
#pragma unroll
    for (int off = 1; off < 1024; off <<= 1) {
        int u = (t >= off) ? sd[t - off] : 0;
        __syncthreads();
        sd[t] += u;
        __syncthreads();
    }
    if (i < N_NODES) rowptr[i] = sd[t] - v;  // exclusive within block
    if (t == 1023) bsum[blockIdx.x] = sd[t];
}
__global__ void k_scan_b(const int* __restrict__ bsum, int* __restrict__ boff,
                         int* __restrict__ rowptr) {
    __shared__ int sd[128];
    int t = threadIdx.x;
    int v = (t < SCAN_B) ? bsum[t] : 0;
    sd[t] = v;
    __syncthreads();
#pragma unroll
    for (int off = 1; off < 128; off <<= 1) {
        int u = (t >= off) ? sd[t - off] : 0;
        __syncthreads();
        sd[t] += u;
        __syncthreads();
    }
    if (t < SCAN_B) boff[t] = sd[t] - v;  // exclusive
    if (t == 0) rowptr[N_NODES] = N_EDGES;  // sum of degrees is exactly E
}
__global__ void k_scan_c(int* __restrict__ rowptr, int* __restrict__ cursor,
                         const int* __restrict__ boff) {
    int i = blockIdx.x * 1024 + threadIdx.x;
    if (i < N_NODES) {
        int r = rowptr[i] + boff[blockIdx.x];
        rowptr[i] = r;
        cursor[i] = r;
    }
}

__global__ void k_scan_clusters(const int* __restrict__ ccount, int* __restrict__ coff,
                                int* __restrict__ ccur) {
    __shared__ int sd[512];
    int t = threadIdx.x;
    sd[t] = (t < NBC) ? ccount[t] : 0;
    __syncthreads();
    for (int off = 1; off < 512; off <<= 1) {
        int v = (t >= off) ? sd[t - off] : 0;
        __syncthreads();
        sd[t] += v;
        __syncthreads();
    }
    if (t < NBC) {
        int ex = (t == 0) ? 0 : sd[t - 1];
        coff[t] = ex;
        ccur[t] = ex;
        if (t == NBC - 1) coff[NBC] = sd[t];
    }
}

__global__ void k_fill_edges(const int* __restrict__ e, int* __restrict__ cursor,
                             int* __restrict__ colx) {
    int i = blockIdx.x * 256 + threadIdx.x;
    if (i < N_EDGES) {
        int d = e[N_EDGES + i];
        int p = atomicAdd(&cursor[d], 1);
        colx[p] = e[i];
    }
}
__global__ void k_fill_nodes(const int* __restrict__ cc, int* __restrict__ ccur,
                             int* __restrict__ cnodes) {
    int i = blockIdx.x * 256 + threadIdx.x;
    if (i < N_NODES) {
        int p = atomicAdd(&ccur[cc[i]], 1);
        cnodes[p] = i;
    }
}

// ================= per-layer: mean of x[src] over incoming edges =================
__global__ void k_aggregate(const bf16* __restrict__ xb, const int* __restrict__ rowptr,
                            const int* __restrict__ colx, bf16* __restrict__ mb) {
    int wave = threadIdx.x >> 6, lane = threadIdx.x & 63;
    int node = blockIdx.x * 4 + wave;
    if (node >= N_NODES) return;
    int lo = rowptr[node], hi = rowptr[node + 1];
    float a0 = 0.f, a1 = 0.f;
    int j = lo;
    int nx = (j < hi) ? colx[j] : 0;
    while (j < hi) {
        int s = nx;
        j++;
        if (j < hi) nx = colx[j];  // prefetch next index to overlap with gather
        __hip_bfloat162 v = *((const __hip_bfloat162*)(xb + (size_t)s * HD) + lane);
        a0 += bf2f(v.x);
        a1 += bf2f(v.y);
    }
    int d = hi - lo;
    float inv = 1.0f / (float)(d > 1 ? d : 1);
    __hip_bfloat162 o;
    o.x = f2bf(a0 * inv);
    o.y = f2bf(a1 * inv);
    *((__hip_bfloat162*)(mb + (size_t)node * HD) + lane) = o;
}

// ================= per-layer: cluster pooling =================
__global__ void k_pool_partial(const float* __restrict__ x, const int* __restrict__ coff,
                               const int* __restrict__ cnodes, float* __restrict__ pf) {
    int cl = blockIdx.x >> 2, seg = blockIdx.x & 3;
    int lo = coff[cl], hi = coff[cl + 1];
    int cnt = hi - lo;
    int per = (cnt + 3) >> 2;
    int s0 = lo + seg * per;
    int s1 = min(s0 + per, hi);
    int col = threadIdx.x & 127, half = threadIdx.x >> 7;
    float a = 0.f;
    for (int i = s0 + half; i < s1; i += 2) a += x[(size_t)cnodes[i] * HD + col];
    __shared__ float red[256];
    red[threadIdx.x] = a;
    __syncthreads();
    if (half == 0) {
        float s = red[col] + red[col + 128];
        atomicAdd(&pf[cl * HD + col], s);
    }
}
__global__ void k_pool_final(const float* __restrict__ pf, const int* __restrict__ ccount,
                             const bf16* __restrict__ tr, bf16* __restrict__ pooled) {
    int i = blockIdx.x * 256 + threadIdx.x;
    int cl = i >> 7;
    int c = ccount[cl];
    float v = pf[i] / (float)(c > 1 ? c : 1) * bf2f(tr[cl]);
    pooled[i] = f2bf(v);
}

// ================= per-layer fused update (two chained MFMA GEMMs + residual) ========
__global__ __launch_bounds__(256) void k_update(
    const bf16* xb, const bf16* __restrict__ mb, const bf16* __restrict__ pooled,
    const bf16* __restrict__ Wmt, const bf16* __restrict__ Wut,
    const bf16* __restrict__ bm, const bf16* __restrict__ bu,
    const int* __restrict__ cc, const int* __restrict__ deg,
    float* __restrict__ x, bf16* xbo) {
    __shared__ __align__(16) short As[64 * LST];
    __shared__ __align__(16) short Ms[64 * LST];
    __shared__ __align__(16) short Gs[64 * LST];
    int tid = threadIdx.x;
    int r0 = blockIdx.x * 64;

    for (int i = tid; i < 1024; i += 256) {
        int row = i >> 4, ch = i & 15;
        int gr = r0 + row;
        s8v vx = {0, 0, 0, 0, 0, 0, 0, 0};
        s8v vm = {0, 0, 0, 0, 0, 0, 0, 0};
        if (gr < N_NODES) {
            vx = *(const s8v*)((const short*)xb + (size_t)gr * HD + ch * 8);
            vm = *(const s8v*)((const short*)mb + (size_t)gr * HD + ch * 8);
        }
        *(s8v*)(As + row * LST + ch * 8) = vx;
        *(s8v*)(Ms + row * LST + ch * 8) = vm;
    }
    __syncthreads();

    int wave = tid >> 6, lane = tid & 63, quad = lane >> 4, nidx = lane & 15;
    int colbase = wave * 32;
    f4v acc[4][2];
#pragma unroll
    for (int rt = 0; rt < 4; rt++)
#pragma unroll
        for (int ct = 0; ct < 2; ct++) acc[rt][ct] = (f4v){0.f, 0.f, 0.f, 0.f};

    // phase 1: [x | m] @ Wm
#pragma unroll
    for (int s = 0; s < 8; s++) {
        int k0 = s * 32;
        const short* Ab = (s < 4) ? As : Ms;
        int kk = (s < 4) ? k0 : (k0 - 128);
        s8v afr[4];
#pragma unroll
        for (int rt = 0; rt < 4; rt++)
            afr[rt] = *(const s8v*)(Ab + (rt * 16 + nidx) * LST + kk + quad * 8);
#pragma unroll
        for (int ct = 0; ct < 2; ct++) {
            s8v bfr = *(const s8v*)((const short*)Wmt + (colbase + ct * 16 + nidx) * 256 + k0 + quad * 8);
#pragma unroll
            for (int rt = 0; rt < 4; rt++)
                acc[rt][ct] = __builtin_amdgcn_mfma_f32_16x16x32_bf16(afr[rt], bfr, acc[rt][ct], 0, 0, 0);
        }
    }
#pragma unroll
    for (int ct = 0; ct < 2; ct++) {
        int col = colbase + ct * 16 + nidx;
        float bmv = bf2f(bm[col]);
#pragma unroll
        for (int rt = 0; rt < 4; rt++) {
#pragma unroll
            for (int r = 0; r < 4; r++) {
                int lrow = rt * 16 + quad * 4 + r;
                int gr = r0 + lrow;
                int d = (gr < N_NODES) ? deg[gr] : 0;
                float v = (d > 0) ? (acc[rt][ct][r] + bmv) : 0.f;
                bf16 h = f2bf(v);
                Gs[lrow * LST + col] = *(short*)&h;
            }
        }
    }
    __syncthreads();

    // phase 2: [x | aggr | pooled[cc]] @ Wu
    int cci[4];
#pragma unroll
    for (int rt = 0; rt < 4; rt++) {
        int gr = r0 + rt * 16 + nidx;
        cci[rt] = (gr < N_NODES) ? cc[gr] : 0;
    }
#pragma unroll
    for (int rt = 0; rt < 4; rt++)
#pragma unroll
        for (int ct = 0; ct < 2; ct++) acc[rt][ct] = (f4v){0.f, 0.f, 0.f, 0.f};
#pragma unroll
    for (int s = 0; s < 12; s++) {
        int k0 = s * 32;
        s8v afr[4];
        if (s < 8) {
            const short* Ab = (s < 4) ? As : Gs;
            int kk = (s < 4) ? k0 : (k0 - 128);
#pragma unroll
            for (int rt = 0; rt < 4; rt++)
                afr[rt] = *(const s8v*)(Ab + (rt * 16 + nidx) * LST + kk + quad * 8);
        } else {
            int kk = k0 - 256;
#pragma unroll
            for (int rt = 0; rt < 4; rt++)
                afr[rt] = *(const s8v*)((const short*)pooled + (size_t)cci[rt] * HD + kk + quad * 8);
        }
#pragma unroll
        for (int ct = 0; ct < 2; ct++) {
            s8v bfr = *(const s8v*)((const short*)Wut + (colbase + ct * 16 + nidx) * 384 + k0 + quad * 8);
#pragma unroll
            for (int rt = 0; rt < 4; rt++)
                acc[rt][ct] = __builtin_amdgcn_mfma_f32_16x16x32_bf16(afr[rt], bfr, acc[rt][ct], 0, 0, 0);
        }
    }
#pragma unroll
    for (int ct = 0; ct < 2; ct++) {
        int col = colbase + ct * 16 + nidx;
        float buv = bf2f(bu[col]);
#pragma unroll
        for (int rt = 0; rt < 4; rt++) {
#pragma unroll
            for (int r = 0; r < 4; r++) {
                int lrow = rt * 16 + quad * 4 + r;
                int gr = r0 + lrow;
                if (gr < N_NODES) {
                    float v = acc[rt][ct][r] + buv;
                    v = (v > 0.f) ? v : 0.01f * v;
                    size_t idx = (size_t)gr * HD + col;
                    float nv = x[idx] + v;
                    x[idx] = nv;
                    xbo[idx] = f2bf(nv);
                }
            }
        }
    }
}

// ================= output (dtype-branched) =================
__global__ void k_output(const int* __restrict__ flags, const float* __restrict__ x,
                         void* __restrict__ out) {
    int i = blockIdx.x * 256 + threadIdx.x;
    if (flags[0]) ((float*)out)[i] = x[i];
    else ((bf16*)out)[i] = f2bf(x[i]);
}

extern "C" void kernel_launch(void* const* d_in, const int* in_sizes, int n_in,
                              void* d_out, int out_size, void* d_ws, size_t ws_size,
                              hipStream_t stream) {
    const void* cf_r = d_in[0];
    const void* slf_r = d_in[1];
    const void* z_r = d_in[2];
    const void* tr_r = d_in[3];
    const void* Wenc_r = d_in[4];
    const void* benc_r = d_in[5];
    const void* Wm_r = d_in[6];
    const void* bm_r = d_in[7];
    const void* Wu_r = d_in[8];
    const void* bu_r = d_in[9];
    const int* e_r = (const int*)d_in[10];
    const int* cc_r = (const int*)d_in[11];

    char* w = (char*)d_ws;
    auto alloc = [&](size_t bytes) -> char* {
        char* p = w;
        w += (bytes + 63) & ~(size_t)63;
        return p;
    };
    float* x = (float*)alloc((size_t)N_NODES * HD * 4);
    bf16* xb = (bf16*)alloc((size_t)N_NODES * HD * 2);
    bf16* mb = (bf16*)alloc((size_t)N_NODES * HD * 2);
    bf16* Wmt = (bf16*)alloc(128 * 256 * 2);
    bf16* Wut = (bf16*)alloc(128 * 384 * 2);
    float* pooledf = (float*)alloc(NBC * HD * 4);
    bf16* pooled = (bf16*)alloc(NBC * HD * 2);
    int* deg = (int*)alloc(N_NODES * 4);
    int* rowptr = (int*)alloc((N_NODES + 1) * 4);
    int* cursor = (int*)alloc(N_NODES * 4);
    int* colx = (int*)alloc(N_EDGES * 4);
    int* ccount = (int*)alloc(NBC * 4);
    int* coff = (int*)alloc((NBC + 1) * 4);
    int* ccur = (int*)alloc(NBC * 4);
    int* cnodes = (int*)alloc(N_NODES * 4);
    int* flags = (int*)alloc(64);
    int* bsum = (int*)alloc(SCAN_B * 4);
    int* boff = (int*)alloc(SCAN_B * 4);
    bf16* cfc = (bf16*)alloc(1500000 * 2);
    bf16* slfc = (bf16*)alloc(100000 * 2);
    bf16* zc = (bf16*)alloc(3200000 * 2);
    bf16* trc = (bf16*)alloc(384 * 2);
    bf16* Wencc = (bf16*)alloc(6144 * 2);
    bf16* bencc = (bf16*)alloc(128 * 2);
    bf16* Wmc = (bf16*)alloc(32768 * 2);
    bf16* bmc = (bf16*)alloc(128 * 2);
    bf16* Wuc = (bf16*)alloc(49152 * 2);
    bf16* buc = (bf16*)alloc(128 * 2);
    int* ec = (int*)alloc(2 * N_EDGES * 4);
    int* ccc = (int*)alloc(N_NODES * 4);

    // dtype detection + canonical conversion
    k_detect<<<1, 64, 0, stream>>>((const unsigned short*)Wenc_r, e_r, flags);
    k_cvt_all<<<C10, 256, 0, stream>>>(flags, cf_r, slf_r, z_r, tr_r, Wenc_r, benc_r,
                                       Wm_r, bm_r, Wu_r, bu_r,
                                       cfc, slfc, zc, trc, Wencc, bencc, Wmc, bmc, Wuc, buc);
    k_cvt_ints<<<B_E + 391, 256, 0, stream>>>(flags, e_r, cc_r, ec, ccc);

    // weight prep + encoder
    k_prep_w<<<(128 * 256 + 128 * 384) / 256, 256, 0, stream>>>(Wmc, Wuc, Wmt, Wut);
    k_encoder<<<N_NODES / 2, 256, 0, stream>>>(cfc, slfc, zc, Wencc, bencc, x, xb);

    // CSR build (edges by dst, nodes by cluster)
    hipMemsetAsync(deg, 0, (size_t)N_NODES * 4, stream);
    hipMemsetAsync(ccount, 0, (size_t)NBC * 4, stream);
    k_count_edges<<<(N_EDGES + 255) / 256, 256, 0, stream>>>(ec, deg);
    k_count_nodes<<<(N_NODES + 255) / 256, 256, 0, stream>>>(ccc, ccount);
    k_scan_a<<<SCAN_B, 1024, 0, stream>>>(deg, rowptr, bsum);
    k_scan_b<<<1, 128, 0, stream>>>(bsum, boff, rowptr);
    k_scan_c<<<SCAN_B, 1024, 0, stream>>>(rowptr, cursor, boff);
    k_scan_clusters<<<1, 512, 0, stream>>>(ccount, coff, ccur);
    k_fill_edges<<<(N_EDGES + 255) / 256, 256, 0, stream>>>(ec, cursor, colx);
    k_fill_nodes<<<(N_NODES + 255) / 256, 256, 0, stream>>>(ccc, ccur, cnodes);

    for (int layer = 0; layer < 3; layer++) {
        hipMemsetAsync(pooledf, 0, (size_t)NBC * HD * 4, stream);
        k_aggregate<<<N_NODES / 4, 256, 0, stream>>>(xb, rowptr, colx, mb);
        k_pool_partial<<<NBC * 4, 256, 0, stream>>>(x, coff, cnodes, pooledf);
        k_pool_final<<<NBC * HD / 256, 256, 0, stream>>>(pooledf, ccount, trc, pooled);
        k_update<<<(N_NODES + 63) / 64, 256, 0, stream>>>(xb, mb, pooled, Wmt, Wut,
                                                          bmc, buc, ccc, deg, x, xb);
    }

    k_output<<<(N_NODES * HD) / 256, 256, 0, stream>>>(flags, x, d_out);
}